// Round 4
// baseline (429.734 us; speedup 1.0000x reference)
//
#include <hip/hip_runtime.h>
#include <hip/hip_bf16.h>

// Problem constants (B,S,M,D,H,DH = 2,1024,1024,1024,16,64)
#define B_ 2
#define S_ 1024
#define M_ 1024
#define D_ 1024
#define H_ 16
#define DH_ 64
#define K_ 2048
#define R_ 4095

// finite stand-in for -inf (avoids inf arithmetic under fast-math)
#define NEG_BIG (-1e30f)

typedef unsigned short u16;
typedef short short8 __attribute__((ext_vector_type(8)));
typedef float f32x4 __attribute__((ext_vector_type(4)));

__device__ __forceinline__ u16 f2bf(float f) {
  __hip_bfloat16 h = __float2bfloat16(f);
  return *reinterpret_cast<u16*>(&h);
}
__device__ __forceinline__ float bf2f(u16 u) {
  __hip_bfloat16 h;
  *reinterpret_cast<u16*>(&h) = u;
  return __bfloat162float(h);
}

// async global->LDS, 16B per lane; LDS dest = wave-uniform base + lane*16
__device__ __forceinline__ void gll16(const void* g, const void* l) {
  __builtin_amdgcn_global_load_lds(
      (const __attribute__((address_space(1))) unsigned int*)g,
      (__attribute__((address_space(3))) unsigned int*)l, 16, 0, 0);
}

__device__ __forceinline__ f32x4 mfma16(short8 a, short8 b, f32x4 c) {
  return __builtin_amdgcn_mfma_f32_16x16x32_bf16(a, b, c, 0, 0, 0);
}

// ---------------- LayerNorm over concat(memory, hidden): f32 in, bf16 out ----------------
__global__ __launch_bounds__(256) void ln_concat_kernel(
    const float* __restrict__ hidden, const float* __restrict__ memory,
    const float* __restrict__ gamma, const float* __restrict__ beta,
    u16* __restrict__ cln) {
  const int row = blockIdx.x;          // 0..B*K-1
  const int b = row >> 11;             // /K_
  const int idx = row & (K_ - 1);
  const float* src = (idx < M_)
      ? memory + (size_t)(b * M_ + idx) * D_
      : hidden + (size_t)(b * S_ + (idx - M_)) * D_;
  const int t = threadIdx.x;
  const int lane = t & 63, w = t >> 6;

  float4 rv = ((const float4*)src)[t];
  float s = rv.x + rv.y + rv.z + rv.w;
  float ss = rv.x * rv.x + rv.y * rv.y + rv.z * rv.z + rv.w * rv.w;
#pragma unroll
  for (int m = 1; m < 64; m <<= 1) {
    s += __shfl_xor(s, m, 64);
    ss += __shfl_xor(ss, m, 64);
  }
  __shared__ float red[8];
  if (lane == 0) { red[w] = s; red[4 + w] = ss; }
  __syncthreads();
  s = red[0] + red[1] + red[2] + red[3];
  ss = red[4] + red[5] + red[6] + red[7];
  const float mu = s * (1.0f / D_);
  const float var = ss * (1.0f / D_) - mu * mu;
  const float rstd = rsqrtf(var + 1e-5f);
  float4 gv = ((const float4*)gamma)[t];
  float4 bv = ((const float4*)beta)[t];
  ushort4 ov;
  ov.x = f2bf((rv.x - mu) * rstd * gv.x + bv.x);
  ov.y = f2bf((rv.y - mu) * rstd * gv.y + bv.y);
  ov.z = f2bf((rv.z - mu) * rstd * gv.z + bv.z);
  ov.w = f2bf((rv.w - mu) * rstd * gv.w + bv.w);
  ((ushort4*)(cln + (size_t)row * D_))[t] = ov;
}

// ---------------- 1024x1024 transpose, f32 in -> bf16 out ----------------
__global__ __launch_bounds__(256) void transpose_kernel(
    const float* __restrict__ in, u16* __restrict__ out) {
  __shared__ u16 tile[64][66];
  const int t = threadIdx.x;
  const int tx = t & 63, ty = t >> 6;
  const int k0 = blockIdx.x * 64, n0 = blockIdx.y * 64;
#pragma unroll
  for (int i = ty; i < 64; i += 4)
    tile[i][tx] = f2bf(in[(size_t)(k0 + i) * D_ + n0 + tx]);
  __syncthreads();
#pragma unroll
  for (int i = ty; i < 64; i += 4)
    out[(size_t)(n0 + i) * D_ + k0 + tx] = tile[tx][i];
}

// ---------------- elementwise f32 -> bf16 (n4 float4 items) ----------------
__global__ __launch_bounds__(256) void cvt_kernel(
    const float* __restrict__ in, u16* __restrict__ out, int n4) {
  const int i = blockIdx.x * 256 + threadIdx.x;
  if (i < n4) {
    float4 v = ((const float4*)in)[i];
    ushort4 o;
    o.x = f2bf(v.x); o.y = f2bf(v.y); o.z = f2bf(v.z); o.w = f2bf(v.w);
    ((ushort4*)out)[i] = o;
  }
}

// row r of the "hidden slice" view -> row of c_ln:  b*K + M + s
__device__ __forceinline__ int maprow_hidden(int r) {
  return r + ((r >> 10) << 10) + M_;
}

// ---------------- GEMM: [M,1024] = A[M,Kd] @ Bt[1024,Kd]^T (+bf16 resid) ----------------
// 128x128 tile, BK=32, 4 waves (2x2), m97-style global_load_lds staging.
// Output: f32 to Cf if non-null, else bf16 to C.
__global__ __launch_bounds__(256, 2) void gemm_bt_kernel(
    const u16* __restrict__ A, const u16* __restrict__ Bt,
    u16* __restrict__ C, float* __restrict__ Cf,
    const u16* __restrict__ resid,
    int Kdim, int a_map, int resid_map) {
  __shared__ __align__(16) u16 As[128 * 32];
  __shared__ __align__(16) u16 Bs[128 * 32];
  const int t = threadIdx.x;
  const int lane = t & 63, w = t >> 6;
  const int wm = w >> 1, wn = w & 1;
  const int qd = lane >> 4, lr = lane & 15;
  const int m0 = blockIdx.y * 128, n0 = blockIdx.x * 128;

  int ar0 = m0 + (t >> 2), ar1 = ar0 + 64;
  if (a_map) { ar0 = maprow_hidden(ar0); ar1 = maprow_hidden(ar1); }
  const u16* Ag0 = A + (size_t)ar0 * Kdim + (t & 3) * 8;
  const u16* Ag1 = A + (size_t)ar1 * Kdim + (t & 3) * 8;
  const u16* Bg0 = Bt + (size_t)(n0 + (t >> 2)) * Kdim + (t & 3) * 8;
  const u16* Bg1 = Bt + (size_t)(n0 + 64 + (t >> 2)) * Kdim + (t & 3) * 8;

  f32x4 acc[4][4];
#pragma unroll
  for (int mt = 0; mt < 4; mt++)
#pragma unroll
    for (int nt = 0; nt < 4; nt++) acc[mt][nt] = (f32x4){0.f, 0.f, 0.f, 0.f};

  for (int kt = 0; kt < Kdim; kt += 32) {
    gll16(Ag0 + kt, As + w * 512);
    gll16(Ag1 + kt, As + 2048 + w * 512);
    gll16(Bg0 + kt, Bs + w * 512);
    gll16(Bg1 + kt, Bs + 2048 + w * 512);
    __syncthreads();
    short8 af[4], bfr[4];
#pragma unroll
    for (int mt = 0; mt < 4; mt++)
      af[mt] = *(const short8*)&As[(wm * 64 + mt * 16 + lr) * 32 + qd * 8];
#pragma unroll
    for (int nt = 0; nt < 4; nt++)
      bfr[nt] = *(const short8*)&Bs[(wn * 64 + nt * 16 + lr) * 32 + qd * 8];
#pragma unroll
    for (int mt = 0; mt < 4; mt++)
#pragma unroll
      for (int nt = 0; nt < 4; nt++)
        acc[mt][nt] = mfma16(af[mt], bfr[nt], acc[mt][nt]);
    __syncthreads();
  }
#pragma unroll
  for (int mt = 0; mt < 4; mt++)
#pragma unroll
    for (int nt = 0; nt < 4; nt++)
#pragma unroll
      for (int r = 0; r < 4; r++) {
        const int row = m0 + wm * 64 + mt * 16 + qd * 4 + r;
        const int col = n0 + wn * 64 + nt * 16 + lr;
        float v = acc[mt][nt][r];
        if (resid) {
          const int rrow = resid_map ? maprow_hidden(row) : row;
          v += bf2f(resid[(size_t)rrow * 1024 + col]);
        }
        if (Cf) Cf[(size_t)row * 1024 + col] = v;
        else    C[(size_t)row * 1024 + col] = f2bf(v);
      }
}

// ---------------- fused rel-pos flash attention (all bf16 operands) ----------------
__global__ __launch_bounds__(256, 2) void attn_kernel(
    const u16* __restrict__ qb, const u16* __restrict__ kb,
    const u16* __restrict__ vb, const u16* __restrict__ pos,
    u16* __restrict__ ab) {
  __shared__ __align__(16) u16 Qs[16 * 64];
  __shared__ __align__(16) u16 Ks[64 * 64];
  __shared__ __align__(16) u16 Vs[64 * 64];
  __shared__ __align__(16) u16 Ps[80 * 64];
  __shared__ __align__(16) float Stile[16 * 64];
  __shared__ __align__(16) u16 Ptile[16 * 64];
  __shared__ __align__(16) float tmp[4][16 * 32];
  __shared__ float alpha_s[16];
  __shared__ float lsum_s[16];

  const int t = threadIdx.x;
  const int lane = t & 63, w = t >> 6;
  const int qd = lane >> 4, lr = lane & 15;
  const int i0 = blockIdx.x * 16;
  const int h = blockIdx.y;
  const int b = blockIdx.z;

  if (w < 2) {
    const int u = t;  // 0..127
    gll16(qb + (size_t)(b * S_ + i0 + (u >> 3)) * 1024 + h * 64 + (u & 7) * 8,
          Qs + w * 512);
  }
  __syncthreads();
  const short8 aQ0 = *(const short8*)&Qs[lr * 64 + qd * 8];
  const short8 aQ1 = *(const short8*)&Qs[lr * 64 + 32 + qd * 8];

  f32x4 accO = {0.f, 0.f, 0.f, 0.f};
  float m_prev = NEG_BIG, l_run = 0.f;
  const int srow = w * 4 + qd;  // row this lane owns in softmax

  const int jmax = min(K_, i0 + 16 + M_);
  for (int j0 = 0; j0 < jmax; j0 += 64) {
#pragma unroll
    for (int rd = 0; rd < 2; rd++) {
      const int u = rd * 256 + t;
      gll16(kb + (size_t)(b * K_ + j0 + (u >> 3)) * 1024 + h * 64 + (u & 7) * 8,
            Ks + rd * 2048 + w * 512);
      gll16(vb + (size_t)(b * K_ + j0 + (u >> 3)) * 1024 + h * 64 + (u & 7) * 8,
            Vs + rd * 2048 + w * 512);
    }
    const int rbase = 1008 + j0 - i0;  // 1023 + j0 - i0 - 15, always >= 0
#pragma unroll
    for (int rd = 0; rd < 2; rd++) {
      const int u = rd * 256 + t;
      gll16(pos + (size_t)(rbase + (u >> 3)) * 64 + (size_t)b * R_ * 64 + (u & 7) * 8,
            Ps + rd * 2048 + w * 512);
    }
    if (w < 2) {
      const int u = 512 + t;  // rows 64..79
      gll16(pos + (size_t)(rbase + (u >> 3)) * 64 + (size_t)b * R_ * 64 + (u & 7) * 8,
            Ps + 4096 + w * 512);
    }
    __syncthreads();

    const short8 bK0 = *(const short8*)&Ks[(w * 16 + lr) * 64 + qd * 8];
    const short8 bK1 = *(const short8*)&Ks[(w * 16 + lr) * 64 + 32 + qd * 8];
    f32x4 sqk = {0.f, 0.f, 0.f, 0.f};
    sqk = mfma16(aQ0, bK0, sqk);
    sqk = mfma16(aQ1, bK1, sqk);
    f32x4 sp0 = {0.f, 0.f, 0.f, 0.f}, sp1 = {0.f, 0.f, 0.f, 0.f};
    {
      short8 bp;
      bp = *(const short8*)&Ps[(w * 16 + lr) * 64 + qd * 8];
      sp0 = mfma16(aQ0, bp, sp0);
      bp = *(const short8*)&Ps[(w * 16 + lr) * 64 + 32 + qd * 8];
      sp0 = mfma16(aQ1, bp, sp0);
      bp = *(const short8*)&Ps[(w * 16 + 16 + lr) * 64 + qd * 8];
      sp1 = mfma16(aQ0, bp, sp1);
      bp = *(const short8*)&Ps[(w * 16 + 16 + lr) * 64 + 32 + qd * 8];
      sp1 = mfma16(aQ1, bp, sp1);
    }
#pragma unroll
    for (int r = 0; r < 4; r++) {
      tmp[w][(qd * 4 + r) * 32 + lr] = sp0[r];
      tmp[w][(qd * 4 + r) * 32 + 16 + lr] = sp1[r];
    }
    __syncthreads();

    // skew gather + scale + causal mask (finite sentinel)
    const int key = j0 + w * 16 + lr;
#pragma unroll
    for (int r = 0; r < 4; r++) {
      const int iL = qd * 4 + r;
      float v = sqk[r] + tmp[w][iL * 32 + 15 + lr - iL];
      v *= 0.03125f;  // 1/sqrt(D)=1/32
      if (key > i0 + iL + M_) v = NEG_BIG;
      Stile[iL * 64 + w * 16 + lr] = v;
    }
    __syncthreads();

    // online softmax: 16 lanes per row, 4 cols per lane
    f32x4 sv = *(const f32x4*)&Stile[srow * 64 + lr * 4];
    float mx = fmaxf(fmaxf(sv[0], sv[1]), fmaxf(sv[2], sv[3]));
#pragma unroll
    for (int msk = 1; msk < 16; msk <<= 1) mx = fmaxf(mx, __shfl_xor(mx, msk, 64));
    const float m_new = fmaxf(m_prev, mx);
    const float al = __expf(m_prev - m_new);
    float p0 = __expf(sv[0] - m_new), p1 = __expf(sv[1] - m_new);
    float p2 = __expf(sv[2] - m_new), p3 = __expf(sv[3] - m_new);
    float psum = p0 + p1 + p2 + p3;
#pragma unroll
    for (int msk = 1; msk < 16; msk <<= 1) psum += __shfl_xor(psum, msk, 64);
    l_run = l_run * al + psum;
    m_prev = m_new;
    {
      ushort4 pq;
      pq.x = f2bf(p0); pq.y = f2bf(p1); pq.z = f2bf(p2); pq.w = f2bf(p3);
      *(ushort4*)&Ptile[srow * 64 + lr * 4] = pq;
    }
    if (lr == 0) alpha_s[srow] = al;
    __syncthreads();

#pragma unroll
    for (int r = 0; r < 4; r++) accO[r] *= alpha_s[qd * 4 + r];
    const short8 aP0 = *(const short8*)&Ptile[lr * 64 + qd * 8];
    const short8 aP1 = *(const short8*)&Ptile[lr * 64 + 32 + qd * 8];
    short8 bV0, bV1;
#pragma unroll
    for (int i = 0; i < 8; i++) {
      bV0[i] = (short)Vs[(qd * 8 + i) * 64 + w * 16 + lr];
      bV1[i] = (short)Vs[(qd * 8 + i + 32) * 64 + w * 16 + lr];
    }
    accO = mfma16(aP0, bV0, accO);
    accO = mfma16(aP1, bV1, accO);
    __syncthreads();
  }

  if (lr == 0) lsum_s[srow] = l_run;
  __syncthreads();
#pragma unroll
  for (int r = 0; r < 4; r++) {
    const int iL = qd * 4 + r;
    const float o = accO[r] / lsum_s[iL];
    ab[(size_t)(b * S_ + i0 + iL) * 1024 + h * 64 + w * 16 + lr] = f2bf(o);
  }
}

// ---------------- launch ----------------
extern "C" void kernel_launch(void* const* d_in, const int* in_sizes, int n_in,
                              void* d_out, int out_size, void* d_ws, size_t ws_size,
                              hipStream_t stream) {
  const float* hidden = (const float*)d_in[0];
  const float* pos    = (const float*)d_in[1];
  const float* memory = (const float*)d_in[2];
  // d_in[3] = mask (bool) — causality applied analytically, unused
  const float* Wq = (const float*)d_in[4];
  const float* Wk = (const float*)d_in[5];
  const float* Wv = (const float*)d_in[6];
  const float* Wo = (const float*)d_in[7];
  const float* gamma = (const float*)d_in[8];
  const float* beta  = (const float*)d_in[9];

  char* ws = (char*)d_ws;
  u16* cln  = (u16*)(ws);               // B*K*D bf16  = 8 MB
  u16* qb   = (u16*)(ws + 8388608);     // 4 MB
  u16* kb   = (u16*)(ws + 12582912);    // 8 MB
  u16* vb   = (u16*)(ws + 20971520);    // 8 MB
  u16* ab   = (u16*)(ws + 29360128);    // 4 MB
  u16* WqT  = (u16*)(ws + 33554432);    // 4 x 2 MB transposed bf16 weights
  u16* WkT  = WqT + 1048576;
  u16* WvT  = WkT + 1048576;
  u16* WoT  = WvT + 1048576;
  u16* posb = (u16*)(ws + 41943040);    // B*R*64 bf16 ≈ 1.0 MB

  ln_concat_kernel<<<dim3(B_ * K_), 256, 0, stream>>>(hidden, memory, gamma, beta, cln);
  dim3 tg(16, 16);
  transpose_kernel<<<tg, 256, 0, stream>>>(Wq, WqT);
  transpose_kernel<<<tg, 256, 0, stream>>>(Wk, WkT);
  transpose_kernel<<<tg, 256, 0, stream>>>(Wv, WvT);
  transpose_kernel<<<tg, 256, 0, stream>>>(Wo, WoT);
  const int n4 = B_ * R_ * 64 / 4;  // 131040 float4 items
  cvt_kernel<<<dim3((n4 + 255) / 256), 256, 0, stream>>>(pos, posb, n4);
  gemm_bt_kernel<<<dim3(8, 16), 256, 0, stream>>>(cln, WqT, qb, nullptr, nullptr, 1024, 1, 0);
  gemm_bt_kernel<<<dim3(8, 32), 256, 0, stream>>>(cln, WkT, kb, nullptr, nullptr, 1024, 0, 0);
  gemm_bt_kernel<<<dim3(8, 32), 256, 0, stream>>>(cln, WvT, vb, nullptr, nullptr, 1024, 0, 0);
  attn_kernel<<<dim3(S_ / 16, H_, B_), 256, 0, stream>>>(qb, kb, vb, posb, ab);
  gemm_bt_kernel<<<dim3(8, 16), 256, 0, stream>>>(ab, WoT, nullptr, (float*)d_out, cln, 1024, 0, 1);
}

// Round 5
// 312.212 us; speedup vs baseline: 1.3764x; 1.3764x over previous
//
#include <hip/hip_runtime.h>
#include <hip/hip_bf16.h>

// Problem constants (B,S,M,D,H,DH = 2,1024,1024,1024,16,64)
#define B_ 2
#define S_ 1024
#define M_ 1024
#define D_ 1024
#define H_ 16
#define DH_ 64
#define K_ 2048
#define R_ 4095

// finite stand-in for -inf (avoids inf arithmetic under fast-math)
#define NEG_BIG (-1e30f)

typedef unsigned short u16;
typedef short short8 __attribute__((ext_vector_type(8)));
typedef float f32x4 __attribute__((ext_vector_type(4)));

__device__ __forceinline__ u16 f2bf(float f) {
  __hip_bfloat16 h = __float2bfloat16(f);
  return *reinterpret_cast<u16*>(&h);
}
__device__ __forceinline__ float bf2f(u16 u) {
  __hip_bfloat16 h;
  *reinterpret_cast<u16*>(&h) = u;
  return __bfloat162float(h);
}

// async global->LDS, 16B per lane; LDS dest = wave-uniform base + lane*16
__device__ __forceinline__ void gll16(const void* g, const void* l) {
  __builtin_amdgcn_global_load_lds(
      (const __attribute__((address_space(1))) unsigned int*)g,
      (__attribute__((address_space(3))) unsigned int*)l, 16, 0, 0);
}

__device__ __forceinline__ f32x4 mfma16(short8 a, short8 b, f32x4 c) {
  return __builtin_amdgcn_mfma_f32_16x16x32_bf16(a, b, c, 0, 0, 0);
}

// ---------------- LayerNorm over concat(memory, hidden): f32 in, bf16 out ----------------
__global__ __launch_bounds__(256) void ln_concat_kernel(
    const float* __restrict__ hidden, const float* __restrict__ memory,
    const float* __restrict__ gamma, const float* __restrict__ beta,
    u16* __restrict__ cln) {
  const int row = blockIdx.x;          // 0..B*K-1
  const int b = row >> 11;             // /K_
  const int idx = row & (K_ - 1);
  const float* src = (idx < M_)
      ? memory + (size_t)(b * M_ + idx) * D_
      : hidden + (size_t)(b * S_ + (idx - M_)) * D_;
  const int t = threadIdx.x;
  const int lane = t & 63, w = t >> 6;

  float4 rv = ((const float4*)src)[t];
  float s = rv.x + rv.y + rv.z + rv.w;
  float ss = rv.x * rv.x + rv.y * rv.y + rv.z * rv.z + rv.w * rv.w;
#pragma unroll
  for (int m = 1; m < 64; m <<= 1) {
    s += __shfl_xor(s, m, 64);
    ss += __shfl_xor(ss, m, 64);
  }
  __shared__ float red[8];
  if (lane == 0) { red[w] = s; red[4 + w] = ss; }
  __syncthreads();
  s = red[0] + red[1] + red[2] + red[3];
  ss = red[4] + red[5] + red[6] + red[7];
  const float mu = s * (1.0f / D_);
  const float var = ss * (1.0f / D_) - mu * mu;
  const float rstd = rsqrtf(var + 1e-5f);
  float4 gv = ((const float4*)gamma)[t];
  float4 bv = ((const float4*)beta)[t];
  ushort4 ov;
  ov.x = f2bf((rv.x - mu) * rstd * gv.x + bv.x);
  ov.y = f2bf((rv.y - mu) * rstd * gv.y + bv.y);
  ov.z = f2bf((rv.z - mu) * rstd * gv.z + bv.z);
  ov.w = f2bf((rv.w - mu) * rstd * gv.w + bv.w);
  ((ushort4*)(cln + (size_t)row * D_))[t] = ov;
}

// ---------------- 4x 1024x1024 transpose, f32 in -> bf16 out (one launch) ----------------
__global__ __launch_bounds__(256) void transpose4_kernel(
    const float* __restrict__ W0, const float* __restrict__ W1,
    const float* __restrict__ W2, const float* __restrict__ W3,
    u16* __restrict__ O0, u16* __restrict__ O1,
    u16* __restrict__ O2, u16* __restrict__ O3) {
  __shared__ u16 tile[64][66];
  const float* in; u16* out;
  switch (blockIdx.z) {
    case 0:  in = W0; out = O0; break;
    case 1:  in = W1; out = O1; break;
    case 2:  in = W2; out = O2; break;
    default: in = W3; out = O3; break;
  }
  const int t = threadIdx.x;
  const int tx = t & 63, ty = t >> 6;
  const int k0 = blockIdx.x * 64, n0 = blockIdx.y * 64;
#pragma unroll
  for (int i = ty; i < 64; i += 4)
    tile[i][tx] = f2bf(in[(size_t)(k0 + i) * D_ + n0 + tx]);
  __syncthreads();
#pragma unroll
  for (int i = ty; i < 64; i += 4)
    out[(size_t)(n0 + i) * D_ + k0 + tx] = tile[tx][i];
}

// ---------------- elementwise f32 -> bf16 (n4 float4 items) ----------------
__global__ __launch_bounds__(256) void cvt_kernel(
    const float* __restrict__ in, u16* __restrict__ out, int n4) {
  const int i = blockIdx.x * 256 + threadIdx.x;
  if (i < n4) {
    float4 v = ((const float4*)in)[i];
    ushort4 o;
    o.x = f2bf(v.x); o.y = f2bf(v.y); o.z = f2bf(v.z); o.w = f2bf(v.w);
    ((ushort4*)out)[i] = o;
  }
}

// row r of the "hidden slice" view -> row of c_ln:  b*K + M + s
__device__ __forceinline__ int maprow_hidden(int r) {
  return r + ((r >> 10) << 10) + M_;
}

// ---------------- GEMM: [M,N] = A[M,Kd] @ Bt[N,Kd]^T ----------------
// 128x128 tile, BK=32, 4 waves (2x2). Modes:
//  kv=1: N=2048; cols<1024 -> C (row-major kb), cols>=1024 -> C2 transposed [b,h,dh,key]
//  kv=0: bf16 to C, or f32 to Cf (+bf16 resid)
__global__ __launch_bounds__(256, 2) void gemm_bt_kernel(
    const u16* __restrict__ A, const u16* __restrict__ Bt,
    u16* __restrict__ C, float* __restrict__ Cf, u16* __restrict__ C2,
    const u16* __restrict__ resid,
    int Kdim, int a_map, int resid_map, int kv) {
  __shared__ __align__(16) u16 As[128 * 32];
  __shared__ __align__(16) u16 Bs[128 * 32];
  const int t = threadIdx.x;
  const int lane = t & 63, w = t >> 6;
  const int wm = w >> 1, wn = w & 1;
  const int qd = lane >> 4, lr = lane & 15;
  const int m0 = blockIdx.y * 128, n0 = blockIdx.x * 128;

  int ar0 = m0 + (t >> 2), ar1 = ar0 + 64;
  if (a_map) { ar0 = maprow_hidden(ar0); ar1 = maprow_hidden(ar1); }
  const u16* Ag0 = A + (size_t)ar0 * Kdim + (t & 3) * 8;
  const u16* Ag1 = A + (size_t)ar1 * Kdim + (t & 3) * 8;
  const u16* Bg0 = Bt + (size_t)(n0 + (t >> 2)) * Kdim + (t & 3) * 8;
  const u16* Bg1 = Bt + (size_t)(n0 + 64 + (t >> 2)) * Kdim + (t & 3) * 8;

  f32x4 acc[4][4];
#pragma unroll
  for (int mt = 0; mt < 4; mt++)
#pragma unroll
    for (int nt = 0; nt < 4; nt++) acc[mt][nt] = (f32x4){0.f, 0.f, 0.f, 0.f};

  for (int kt = 0; kt < Kdim; kt += 32) {
    gll16(Ag0 + kt, As + w * 512);
    gll16(Ag1 + kt, As + 2048 + w * 512);
    gll16(Bg0 + kt, Bs + w * 512);
    gll16(Bg1 + kt, Bs + 2048 + w * 512);
    __syncthreads();
    short8 af[4], bfr[4];
#pragma unroll
    for (int mt = 0; mt < 4; mt++)
      af[mt] = *(const short8*)&As[(wm * 64 + mt * 16 + lr) * 32 + qd * 8];
#pragma unroll
    for (int nt = 0; nt < 4; nt++)
      bfr[nt] = *(const short8*)&Bs[(wn * 64 + nt * 16 + lr) * 32 + qd * 8];
#pragma unroll
    for (int mt = 0; mt < 4; mt++)
#pragma unroll
      for (int nt = 0; nt < 4; nt++)
        acc[mt][nt] = mfma16(af[mt], bfr[nt], acc[mt][nt]);
    __syncthreads();
  }

  if (kv) {
#pragma unroll
    for (int mt = 0; mt < 4; mt++)
#pragma unroll
      for (int nt = 0; nt < 4; nt++) {
        const int colb = n0 + wn * 64 + nt * 16;        // 16-aligned
        const int rowb = m0 + wm * 64 + mt * 16 + qd * 4;
        if (colb < 1024) {                               // K part -> kb row-major
#pragma unroll
          for (int r = 0; r < 4; r++)
            C[(size_t)(rowb + r) * 1024 + colb + lr] = f2bf(acc[mt][nt][r]);
        } else {                                         // V part -> vbT [b*H+h][dh][key]
          const int nn = colb - 1024 + lr;               // h*64+dh
          const int bh = (rowb >> 11) * H_ + (nn >> 6);
          const int dh = nn & 63;
          const int key = rowb & (K_ - 1);
          ushort4 pk;
          pk.x = f2bf(acc[mt][nt][0]);
          pk.y = f2bf(acc[mt][nt][1]);
          pk.z = f2bf(acc[mt][nt][2]);
          pk.w = f2bf(acc[mt][nt][3]);
          *(ushort4*)&C2[((size_t)bh * 64 + dh) * K_ + key] = pk;
        }
      }
    return;
  }

#pragma unroll
  for (int mt = 0; mt < 4; mt++)
#pragma unroll
    for (int nt = 0; nt < 4; nt++)
#pragma unroll
      for (int r = 0; r < 4; r++) {
        const int row = m0 + wm * 64 + mt * 16 + qd * 4 + r;
        const int col = n0 + wn * 64 + nt * 16 + lr;
        float v = acc[mt][nt][r];
        if (resid) {
          const int rrow = resid_map ? maprow_hidden(row) : row;
          v += bf2f(resid[(size_t)rrow * 1024 + col]);
        }
        if (Cf) Cf[(size_t)row * 1024 + col] = v;
        else    C[(size_t)row * 1024 + col] = f2bf(v);
      }
}

// ---------------- fused rel-pos flash attention, v2 ----------------
// grid (S/64, H, B), 256 threads. Wave w privately owns Q rows [16w,16w+16):
// no cross-wave softmax state; only K/Vt/pos staging is block-shared.
// 2 barriers per 64-key tile; 26 MFMAs/wave between barriers.
__global__ __launch_bounds__(256, 2) void attn_kernel(
    const u16* __restrict__ qb, const u16* __restrict__ kb,
    const u16* __restrict__ vbT, const u16* __restrict__ pos,
    u16* __restrict__ ab) {
  __shared__ __align__(16) u16 Ks[64 * 64];      //  8 KB  [key][dh]
  __shared__ __align__(16) u16 Vt[64 * 64];      //  8 KB  [dh][key]
  __shared__ __align__(16) u16 Ps[128 * 64];     // 16 KB  pos band [bandrow][dh]
  __shared__ __align__(16) float tmp[4][16 * 80];// 20 KB  wave-private pos scores
  __shared__ __align__(16) u16 Pt[4][16 * 64];   //  8 KB  wave-private P tiles
  u16* Qs = (u16*)&tmp[0][0];                    // aliased: only used before main loop

  const int t = threadIdx.x;
  const int lane = t & 63, w = t >> 6;
  const int qd = lane >> 4, lr = lane & 15;
  const int i0 = blockIdx.x * 64;
  const int h = blockIdx.y;
  const int b = blockIdx.z;

  // stage Q (64x64) into aliased region, read this wave's A-fragments
#pragma unroll
  for (int rd = 0; rd < 2; rd++) {
    const int u = rd * 256 + t;
    gll16(qb + (size_t)(b * S_ + i0 + (u >> 3)) * 1024 + h * 64 + (u & 7) * 8,
          Qs + rd * 2048 + w * 512);
  }
  __syncthreads();
  const short8 aQ0 = *(const short8*)&Qs[(w * 16 + lr) * 64 + qd * 8];
  const short8 aQ1 = *(const short8*)&Qs[(w * 16 + lr) * 64 + 32 + qd * 8];

  f32x4 accO[4];
#pragma unroll
  for (int d = 0; d < 4; d++) accO[d] = (f32x4){0.f, 0.f, 0.f, 0.f};
  float m_prev[4], l_run[4];
#pragma unroll
  for (int r = 0; r < 4; r++) { m_prev[r] = NEG_BIG; l_run[r] = 0.f; }

  const int bw = 48 - w * 16;                    // wave's pos-band column offset
  const int jmax = min(K_, i0 + 64 + M_);
  for (int j0 = 0; j0 < jmax; j0 += 64) {
    __syncthreads();  // previous tile's LDS reads (and Q-frag reads) complete
#pragma unroll
    for (int rd = 0; rd < 2; rd++) {
      const int u = rd * 256 + t;
      gll16(kb + (size_t)(b * K_ + j0 + (u >> 3)) * 1024 + h * 64 + (u & 7) * 8,
            Ks + rd * 2048 + w * 512);
      gll16(vbT + (size_t)((b * H_ + h) * 64 + (u >> 3)) * K_ + j0 + (u & 7) * 8,
            Vt + rd * 2048 + w * 512);
    }
    const int rbase = 960 + j0 - i0;             // band rows rbase..rbase+127, all in [0,R)
#pragma unroll
    for (int rd = 0; rd < 4; rd++) {
      const int u = rd * 256 + t;
      gll16(pos + (size_t)(b * R_ + rbase + (u >> 3)) * 64 + (u & 7) * 8,
            Ps + rd * 2048 + w * 512);
    }
    __syncthreads();  // staging visible

    // ---- QK^T: 16 rows x 64 keys ----
    f32x4 sqk[4];
#pragma unroll
    for (int kc = 0; kc < 4; kc++) {
      const short8 bK0 = *(const short8*)&Ks[(kc * 16 + lr) * 64 + qd * 8];
      const short8 bK1 = *(const short8*)&Ks[(kc * 16 + lr) * 64 + 32 + qd * 8];
      f32x4 z = {0.f, 0.f, 0.f, 0.f};
      z = mfma16(aQ0, bK0, z);
      sqk[kc] = mfma16(aQ1, bK1, z);
    }
    // ---- Q @ pos-band^T: 16 rows x 80 band cols -> wave-private tmp ----
#pragma unroll
    for (int pc = 0; pc < 5; pc++) {
      const short8 bP0 = *(const short8*)&Ps[(bw + pc * 16 + lr) * 64 + qd * 8];
      const short8 bP1 = *(const short8*)&Ps[(bw + pc * 16 + lr) * 64 + 32 + qd * 8];
      f32x4 z = {0.f, 0.f, 0.f, 0.f};
      z = mfma16(aQ0, bP0, z);
      z = mfma16(aQ1, bP1, z);
#pragma unroll
      for (int r = 0; r < 4; r++)
        tmp[w][(qd * 4 + r) * 80 + pc * 16 + lr] = z[r];
    }
    __asm__ volatile("s_waitcnt lgkmcnt(0)" ::: "memory");

    // ---- skew gather + scale + mask ----
    float s[4][4];
#pragma unroll
    for (int kc = 0; kc < 4; kc++)
#pragma unroll
      for (int r = 0; r < 4; r++) {
        const int iL = qd * 4 + r;
        float v = (sqk[kc][r] + tmp[w][iL * 80 + 15 + kc * 16 + lr - iL]) * 0.03125f;
        if (j0 + kc * 16 + lr > i0 + w * 16 + iL + M_) v = NEG_BIG;
        s[kc][r] = v;
      }

    // ---- online softmax (16 lanes per row, within-wave shuffles only) ----
    float al[4], p[4][4];
#pragma unroll
    for (int r = 0; r < 4; r++) {
      float mx = fmaxf(fmaxf(s[0][r], s[1][r]), fmaxf(s[2][r], s[3][r]));
#pragma unroll
      for (int msk = 1; msk < 16; msk <<= 1) mx = fmaxf(mx, __shfl_xor(mx, msk, 64));
      const float m_new = fmaxf(m_prev[r], mx);
      al[r] = __expf(m_prev[r] - m_new);
      float ps = 0.f;
#pragma unroll
      for (int kc = 0; kc < 4; kc++) { p[kc][r] = __expf(s[kc][r] - m_new); ps += p[kc][r]; }
#pragma unroll
      for (int msk = 1; msk < 16; msk <<= 1) ps += __shfl_xor(ps, msk, 64);
      l_run[r] = l_run[r] * al[r] + ps;
      m_prev[r] = m_new;
    }

    // ---- P -> wave-private LDS (C-layout) -> A-fragments ----
#pragma unroll
    for (int kc = 0; kc < 4; kc++)
#pragma unroll
      for (int r = 0; r < 4; r++)
        Pt[w][(qd * 4 + r) * 64 + kc * 16 + lr] = f2bf(p[kc][r]);
    __asm__ volatile("s_waitcnt lgkmcnt(0)" ::: "memory");
    const short8 aP0 = *(const short8*)&Pt[w][lr * 64 + qd * 8];
    const short8 aP1 = *(const short8*)&Pt[w][lr * 64 + 32 + qd * 8];

    // ---- rescale O, P @ V ----
#pragma unroll
    for (int d = 0; d < 4; d++)
#pragma unroll
      for (int r = 0; r < 4; r++) accO[d][r] *= al[r];
#pragma unroll
    for (int d = 0; d < 4; d++) {
      const short8 bV0 = *(const short8*)&Vt[(d * 16 + lr) * 64 + qd * 8];
      const short8 bV1 = *(const short8*)&Vt[(d * 16 + lr) * 64 + 32 + qd * 8];
      accO[d] = mfma16(aP0, bV0, accO[d]);
      accO[d] = mfma16(aP1, bV1, accO[d]);
    }
  }

  // ---- epilogue ----
#pragma unroll
  for (int d = 0; d < 4; d++)
#pragma unroll
    for (int r = 0; r < 4; r++) {
      const int iG = i0 + w * 16 + qd * 4 + r;
      const float o = accO[d][r] / l_run[r];
      ab[(size_t)(b * S_ + iG) * 1024 + h * 64 + d * 16 + lr] = f2bf(o);
    }
}

// ---------------- launch ----------------
extern "C" void kernel_launch(void* const* d_in, const int* in_sizes, int n_in,
                              void* d_out, int out_size, void* d_ws, size_t ws_size,
                              hipStream_t stream) {
  const float* hidden = (const float*)d_in[0];
  const float* pos    = (const float*)d_in[1];
  const float* memory = (const float*)d_in[2];
  // d_in[3] = mask (bool) — causality applied analytically, unused
  const float* Wq = (const float*)d_in[4];
  const float* Wk = (const float*)d_in[5];
  const float* Wv = (const float*)d_in[6];
  const float* Wo = (const float*)d_in[7];
  const float* gamma = (const float*)d_in[8];
  const float* beta  = (const float*)d_in[9];

  char* ws = (char*)d_ws;
  u16* cln  = (u16*)(ws);               // B*K*D bf16  = 8 MB
  u16* qb   = (u16*)(ws + 8388608);     // 4 MB  [b][s][h*64+dh]
  u16* kb   = (u16*)(ws + 12582912);    // 8 MB  [b][key][h*64+dh]
  u16* vbT  = (u16*)(ws + 20971520);    // 8 MB  [b*H+h][dh][key]
  u16* ab   = (u16*)(ws + 29360128);    // 4 MB
  u16* WqT  = (u16*)(ws + 33554432);    // 4 x 2 MB transposed bf16 weights (contiguous)
  u16* WkT  = WqT + 1048576;
  u16* WvT  = WkT + 1048576;
  u16* WoT  = WvT + 1048576;
  u16* posb = (u16*)(ws + 41943040);    // B*R*64 bf16 ≈ 1.0 MB

  ln_concat_kernel<<<dim3(B_ * K_), 256, 0, stream>>>(hidden, memory, gamma, beta, cln);
  transpose4_kernel<<<dim3(16, 16, 4), 256, 0, stream>>>(Wq, Wk, Wv, Wo, WqT, WkT, WvT, WoT);
  const int n4 = B_ * R_ * 64 / 4;
  cvt_kernel<<<dim3((n4 + 255) / 256), 256, 0, stream>>>(pos, posb, n4);
  // Q = h_ln @ Wq
  gemm_bt_kernel<<<dim3(8, 16), 256, 0, stream>>>(cln, WqT, qb, nullptr, nullptr, nullptr, 1024, 1, 0, 0);
  // K,V fused: Bt = WkT||WvT (contiguous), N=2048; V written transposed
  gemm_bt_kernel<<<dim3(16, 32), 256, 0, stream>>>(cln, WkT, kb, nullptr, vbT, nullptr, 1024, 0, 0, 1);
  attn_kernel<<<dim3(S_ / 64, H_, B_), 256, 0, stream>>>(qb, kb, vbT, posb, ab);
  // out = h_ln + attn @ Wo
  gemm_bt_kernel<<<dim3(8, 16), 256, 0, stream>>>(ab, WoT, nullptr, (float*)d_out, nullptr, cln, 1024, 0, 1, 0);
}

// Round 6
// 251.101 us; speedup vs baseline: 1.7114x; 1.2434x over previous
//
#include <hip/hip_runtime.h>
#include <hip/hip_bf16.h>

// Problem constants (B,S,M,D,H,DH = 2,1024,1024,1024,16,64)
#define B_ 2
#define S_ 1024
#define M_ 1024
#define D_ 1024
#define H_ 16
#define DH_ 64
#define K_ 2048
#define R_ 4095

// finite stand-in for -inf (avoids inf arithmetic under fast-math)
#define NEG_BIG (-1e30f)

typedef unsigned short u16;
typedef short short8 __attribute__((ext_vector_type(8)));
typedef float f32x4 __attribute__((ext_vector_type(4)));

__device__ __forceinline__ u16 f2bf(float f) {
  __hip_bfloat16 h = __float2bfloat16(f);
  return *reinterpret_cast<u16*>(&h);
}
__device__ __forceinline__ float bf2f(u16 u) {
  __hip_bfloat16 h;
  *reinterpret_cast<u16*>(&h) = u;
  return __bfloat162float(h);
}
__device__ __forceinline__ u16 bfbits(__hip_bfloat16 h) {
  return *reinterpret_cast<u16*>(&h);
}

// async global->LDS, 16B per lane; LDS dest = wave-uniform base + lane*16
__device__ __forceinline__ void gll16(const void* g, const void* l) {
  __builtin_amdgcn_global_load_lds(
      (const __attribute__((address_space(1))) unsigned int*)g,
      (__attribute__((address_space(3))) unsigned int*)l, 16, 0, 0);
}

__device__ __forceinline__ f32x4 mfma16(short8 a, short8 b, f32x4 c) {
  return __builtin_amdgcn_mfma_f32_16x16x32_bf16(a, b, c, 0, 0, 0);
}

// ---------------- fused prep: LN(concat) + 4x weight transpose + pos cvt ----------------
// grid: [0,4096) LN rows; [4096,5120) transpose (4 slabs x 256 blocks); [5120,5632) cvt
__global__ __launch_bounds__(256) void prep_kernel(
    const float* __restrict__ hidden, const float* __restrict__ memory,
    const float* __restrict__ gamma, const float* __restrict__ beta,
    u16* __restrict__ cln,
    const float* __restrict__ W0, const float* __restrict__ W1,
    const float* __restrict__ W2, const float* __restrict__ W3,
    u16* __restrict__ O0, u16* __restrict__ O1,
    u16* __restrict__ O2, u16* __restrict__ O3,
    const float* __restrict__ pos, u16* __restrict__ posb) {
  __shared__ u16 tile[64][66];
  __shared__ float red[8];
  const int bx = blockIdx.x;
  const int t = threadIdx.x;

  if (bx < 4096) {  // ---- LayerNorm row ----
    const int b = bx >> 11;
    const int idx = bx & (K_ - 1);
    const float* src = (idx < M_)
        ? memory + (size_t)(b * M_ + idx) * D_
        : hidden + (size_t)(b * S_ + (idx - M_)) * D_;
    const int lane = t & 63, w = t >> 6;
    float4 rv = ((const float4*)src)[t];
    float s = rv.x + rv.y + rv.z + rv.w;
    float ss = rv.x * rv.x + rv.y * rv.y + rv.z * rv.z + rv.w * rv.w;
#pragma unroll
    for (int m = 1; m < 64; m <<= 1) {
      s += __shfl_xor(s, m, 64);
      ss += __shfl_xor(ss, m, 64);
    }
    if (lane == 0) { red[w] = s; red[4 + w] = ss; }
    __syncthreads();
    s = red[0] + red[1] + red[2] + red[3];
    ss = red[4] + red[5] + red[6] + red[7];
    const float mu = s * (1.0f / D_);
    const float var = ss * (1.0f / D_) - mu * mu;
    const float rstd = rsqrtf(var + 1e-5f);
    float4 gv = ((const float4*)gamma)[t];
    float4 bv = ((const float4*)beta)[t];
    ushort4 ov;
    ov.x = f2bf((rv.x - mu) * rstd * gv.x + bv.x);
    ov.y = f2bf((rv.y - mu) * rstd * gv.y + bv.y);
    ov.z = f2bf((rv.z - mu) * rstd * gv.z + bv.z);
    ov.w = f2bf((rv.w - mu) * rstd * gv.w + bv.w);
    ((ushort4*)(cln + (size_t)bx * D_))[t] = ov;
    return;
  }
  if (bx < 5120) {  // ---- weight transpose slab ----
    const int z = (bx - 4096) >> 8;
    const int rem = (bx - 4096) & 255;
    const float* in; u16* out;
    switch (z) {
      case 0:  in = W0; out = O0; break;
      case 1:  in = W1; out = O1; break;
      case 2:  in = W2; out = O2; break;
      default: in = W3; out = O3; break;
    }
    const int tx = t & 63, ty = t >> 6;
    const int k0 = (rem & 15) * 64, n0 = (rem >> 4) * 64;
#pragma unroll
    for (int i = ty; i < 64; i += 4)
      tile[i][tx] = f2bf(in[(size_t)(k0 + i) * D_ + n0 + tx]);
    __syncthreads();
#pragma unroll
    for (int i = ty; i < 64; i += 4)
      out[(size_t)(n0 + i) * D_ + k0 + tx] = tile[tx][i];
    return;
  }
  // ---- pos f32 -> bf16 ----
  const int i = (bx - 5120) * 256 + t;
  const int n4 = B_ * R_ * 64 / 4;
  if (i < n4) {
    float4 v = ((const float4*)pos)[i];
    ushort4 o;
    o.x = f2bf(v.x); o.y = f2bf(v.y); o.z = f2bf(v.z); o.w = f2bf(v.w);
    ((ushort4*)posb)[i] = o;
  }
}

// row r of the "hidden slice" view -> row of c_ln:  b*K + M + s
__device__ __forceinline__ int maprow_hidden(int r) {
  return r + ((r >> 10) << 10) + M_;
}

// ---------------- GEMM: [M,N] = A[M,Kd] @ Bt[N,Kd]^T ----------------
// 128x128 tile, BK=32, 4 waves (2x2).
//  qkv=1: A = full c_ln (4096 rows), Bt = WqT||WkT||WvT (N=3072):
//         n<1024 -> qb (hidden rows only); n<2048 -> kb; else vbT [b*H+h][dh][key]
//  qkv=0: f32 out to Cf (+bf16 resid via maprow)
__global__ __launch_bounds__(256, 2) void gemm_bt_kernel(
    const u16* __restrict__ A, const u16* __restrict__ Bt,
    u16* __restrict__ qb, u16* __restrict__ kb, u16* __restrict__ vbT,
    float* __restrict__ Cf, const u16* __restrict__ resid,
    int Kdim, int a_map, int resid_map, int qkv) {
  __shared__ __align__(16) u16 As[128 * 32];
  __shared__ __align__(16) u16 Bs[128 * 32];
  const int t = threadIdx.x;
  const int lane = t & 63, w = t >> 6;
  const int wm = w >> 1, wn = w & 1;
  const int qd = lane >> 4, lr = lane & 15;
  const int m0 = blockIdx.y * 128, n0 = blockIdx.x * 128;

  int ar0 = m0 + (t >> 2), ar1 = ar0 + 64;
  if (a_map) { ar0 = maprow_hidden(ar0); ar1 = maprow_hidden(ar1); }
  const u16* Ag0 = A + (size_t)ar0 * Kdim + (t & 3) * 8;
  const u16* Ag1 = A + (size_t)ar1 * Kdim + (t & 3) * 8;
  const u16* Bg0 = Bt + (size_t)(n0 + (t >> 2)) * Kdim + (t & 3) * 8;
  const u16* Bg1 = Bt + (size_t)(n0 + 64 + (t >> 2)) * Kdim + (t & 3) * 8;

  f32x4 acc[4][4];
#pragma unroll
  for (int mt = 0; mt < 4; mt++)
#pragma unroll
    for (int nt = 0; nt < 4; nt++) acc[mt][nt] = (f32x4){0.f, 0.f, 0.f, 0.f};

  for (int kt = 0; kt < Kdim; kt += 32) {
    gll16(Ag0 + kt, As + w * 512);
    gll16(Ag1 + kt, As + 2048 + w * 512);
    gll16(Bg0 + kt, Bs + w * 512);
    gll16(Bg1 + kt, Bs + 2048 + w * 512);
    __syncthreads();
    short8 af[4], bfr[4];
#pragma unroll
    for (int mt = 0; mt < 4; mt++)
      af[mt] = *(const short8*)&As[(wm * 64 + mt * 16 + lr) * 32 + qd * 8];
#pragma unroll
    for (int nt = 0; nt < 4; nt++)
      bfr[nt] = *(const short8*)&Bs[(wn * 64 + nt * 16 + lr) * 32 + qd * 8];
#pragma unroll
    for (int mt = 0; mt < 4; mt++)
#pragma unroll
      for (int nt = 0; nt < 4; nt++)
        acc[mt][nt] = mfma16(af[mt], bfr[nt], acc[mt][nt]);
    __syncthreads();
  }

  if (qkv) {
#pragma unroll
    for (int mt = 0; mt < 4; mt++)
#pragma unroll
      for (int nt = 0; nt < 4; nt++) {
        const int colb = n0 + wn * 64 + nt * 16;         // 16-aligned
        const int rowb = m0 + wm * 64 + mt * 16 + qd * 4;
        if (colb < 1024) {                               // Q: hidden rows only
          if (rowb & 1024) {
            const int qrow = ((rowb >> 11) << 10) | (rowb & 1023);
#pragma unroll
            for (int r = 0; r < 4; r++)
              qb[(size_t)(qrow + r) * 1024 + colb + lr] = f2bf(acc[mt][nt][r]);
          }
        } else if (colb < 2048) {                        // K row-major
          const int key = rowb & (K_ - 1);
          const int bq = rowb >> 11;
#pragma unroll
          for (int r = 0; r < 4; r++)
            kb[(size_t)(bq * K_ + key + r) * 1024 + (colb - 1024) + lr] = f2bf(acc[mt][nt][r]);
        } else {                                         // V transposed [b*H+h][dh][key]
          const int nn = colb - 2048 + lr;
          const int bh = ((rowb >> 11) << 4) | (nn >> 6);
          const int dh = nn & 63;
          const int key = rowb & (K_ - 1);
          ushort4 pk;
          pk.x = f2bf(acc[mt][nt][0]);
          pk.y = f2bf(acc[mt][nt][1]);
          pk.z = f2bf(acc[mt][nt][2]);
          pk.w = f2bf(acc[mt][nt][3]);
          *(ushort4*)&vbT[((size_t)bh * 64 + dh) * K_ + key] = pk;
        }
      }
    return;
  }

#pragma unroll
  for (int mt = 0; mt < 4; mt++)
#pragma unroll
    for (int nt = 0; nt < 4; nt++)
#pragma unroll
      for (int r = 0; r < 4; r++) {
        const int row = m0 + wm * 64 + mt * 16 + qd * 4 + r;
        const int col = n0 + wn * 64 + nt * 16 + lr;
        float v = acc[mt][nt][r];
        const int rrow = resid_map ? maprow_hidden(row) : row;
        v += bf2f(resid[(size_t)rrow * 1024 + col]);
        Cf[(size_t)row * 1024 + col] = v;
      }
}

// ---------------- fused rel-pos flash attention, v3 (XOR-swizzled staging) ----------------
// grid (S/64, H, B), 256 threads. Wave w privately owns Q rows [16w,16w+16).
// Staging swizzle: LDS slot (row, chunk c) holds global chunk c ^ (row&7);
// fragment reads use chunk qd ^ (lr&7) -> 2-way banks (free).
__global__ __launch_bounds__(256, 2) void attn_kernel(
    const u16* __restrict__ qb, const u16* __restrict__ kb,
    const u16* __restrict__ vbT, const u16* __restrict__ pos,
    u16* __restrict__ ab) {
  __shared__ __align__(16) u16 Ks[64 * 64];        //  8 KB  [key][dh]   (swizzled)
  __shared__ __align__(16) u16 Vt[64 * 64];        //  8 KB  [dh][key]   (swizzled)
  __shared__ __align__(16) u16 Ps[128 * 64];       // 16 KB  pos band    (swizzled)
  __shared__ __align__(16) float tmp[4][16 * 83];  // ~21 KB wave-private pos scores
  __shared__ __align__(16) u16 Pt[4][16 * 68];     // ~8.5KB wave-private P tiles
  u16* Qs = (u16*)&tmp[0][0];                      // 8 KB alias, used only pre-loop

  const int t = threadIdx.x;
  const int lane = t & 63, w = t >> 6;
  const int qd = lane >> 4, lr = lane & 15;
  const int i0 = blockIdx.x * 64;
  const int h = blockIdx.y;
  const int b = blockIdx.z;

  // staging source-chunk swizzle for this thread's slot in a 256-lane pass
  const int swz = ((t & 7) ^ ((t >> 3) & 7)) * 8;  // element offset of chunk
  // fragment-read chunk offsets (row&7 == lr&7 for all our row bases)
  const int c0 = (qd ^ (lr & 7)) * 8;
  const int c1 = c0 ^ 32;

  // ---- stage Q (64x64) swizzled into aliased region ----
#pragma unroll
  for (int rd = 0; rd < 2; rd++) {
    const int row = rd * 32 + (t >> 3);
    gll16(qb + (size_t)(b * S_ + i0 + row) * 1024 + h * 64 + swz,
          Qs + rd * 2048 + w * 512);
  }
  __syncthreads();
  const short8 aQ0 = *(const short8*)&Qs[(w * 16 + lr) * 64 + c0];
  const short8 aQ1 = *(const short8*)&Qs[(w * 16 + lr) * 64 + c1];

  f32x4 accO[4];
#pragma unroll
  for (int d = 0; d < 4; d++) accO[d] = (f32x4){0.f, 0.f, 0.f, 0.f};
  float m_prev[4], l_run[4];
#pragma unroll
  for (int r = 0; r < 4; r++) { m_prev[r] = NEG_BIG; l_run[r] = 0.f; }

  const int bw = 48 - w * 16;  // wave's pos-band offset (multiple of 16)
  const int jmax = min(K_, i0 + 64 + M_);
  for (int j0 = 0; j0 < jmax; j0 += 64) {
    __syncthreads();  // previous tile's LDS reads complete
#pragma unroll
    for (int rd = 0; rd < 2; rd++) {
      const int row = rd * 32 + (t >> 3);
      gll16(kb + (size_t)(b * K_ + j0 + row) * 1024 + h * 64 + swz,
            Ks + rd * 2048 + w * 512);
      gll16(vbT + (size_t)((b * H_ + h) * 64 + row) * K_ + j0 + swz,
            Vt + rd * 2048 + w * 512);
    }
    const int rbase = 960 + j0 - i0;  // band rows rbase..rbase+127, all in [0,R)
#pragma unroll
    for (int rd = 0; rd < 4; rd++) {
      const int row = rd * 32 + (t >> 3);
      gll16(pos + (size_t)(b * R_ + rbase + row) * 64 + swz,
            Ps + rd * 2048 + w * 512);
    }
    __syncthreads();  // staging visible

    // ---- QK^T: 16 rows x 64 keys ----
    f32x4 sqk[4];
#pragma unroll
    for (int kc = 0; kc < 4; kc++) {
      const short8 bK0 = *(const short8*)&Ks[(kc * 16 + lr) * 64 + c0];
      const short8 bK1 = *(const short8*)&Ks[(kc * 16 + lr) * 64 + c1];
      f32x4 z = {0.f, 0.f, 0.f, 0.f};
      z = mfma16(aQ0, bK0, z);
      sqk[kc] = mfma16(aQ1, bK1, z);
    }
    // ---- Q @ pos-band^T: 16 rows x 80 band cols -> wave-private tmp ----
#pragma unroll
    for (int pc = 0; pc < 5; pc++) {
      const short8 bP0 = *(const short8*)&Ps[(bw + pc * 16 + lr) * 64 + c0];
      const short8 bP1 = *(const short8*)&Ps[(bw + pc * 16 + lr) * 64 + c1];
      f32x4 z = {0.f, 0.f, 0.f, 0.f};
      z = mfma16(aQ0, bP0, z);
      z = mfma16(aQ1, bP1, z);
#pragma unroll
      for (int r = 0; r < 4; r++)
        tmp[w][(qd * 4 + r) * 83 + pc * 16 + lr] = z[r];
    }
    __asm__ volatile("s_waitcnt lgkmcnt(0)" ::: "memory");

    // ---- skew gather + scale + mask ----
    float s[4][4];
#pragma unroll
    for (int kc = 0; kc < 4; kc++)
#pragma unroll
      for (int r = 0; r < 4; r++) {
        const int iL = qd * 4 + r;
        float v = (sqk[kc][r] + tmp[w][iL * 83 + 15 + kc * 16 + lr - iL]) * 0.03125f;
        if (j0 + kc * 16 + lr > i0 + w * 16 + iL + M_) v = NEG_BIG;
        s[kc][r] = v;
      }

    // ---- online softmax (16 lanes per row, within-wave shuffles) ----
    float al[4], p[4][4];
#pragma unroll
    for (int r = 0; r < 4; r++) {
      float mx = fmaxf(fmaxf(s[0][r], s[1][r]), fmaxf(s[2][r], s[3][r]));
#pragma unroll
      for (int msk = 1; msk < 16; msk <<= 1) mx = fmaxf(mx, __shfl_xor(mx, msk, 64));
      const float m_new = fmaxf(m_prev[r], mx);
      al[r] = __expf(m_prev[r] - m_new);
      float ps = 0.f;
#pragma unroll
      for (int kc = 0; kc < 4; kc++) { p[kc][r] = __expf(s[kc][r] - m_new); ps += p[kc][r]; }
#pragma unroll
      for (int msk = 1; msk < 16; msk <<= 1) ps += __shfl_xor(ps, msk, 64);
      l_run[r] = l_run[r] * al[r] + ps;
      m_prev[r] = m_new;
    }

    // ---- P -> wave-private LDS (C-layout, padded stride) -> A-fragments ----
#pragma unroll
    for (int r = 0; r < 4; r++) {
      __hip_bfloat162 pk01 = __float22bfloat162_rn(make_float2(p[0][r], p[1][r]));
      __hip_bfloat162 pk23 = __float22bfloat162_rn(make_float2(p[2][r], p[3][r]));
      const int base = (qd * 4 + r) * 68 + lr;
      Pt[w][base +  0] = bfbits(pk01.x);
      Pt[w][base + 16] = bfbits(pk01.y);
      Pt[w][base + 32] = bfbits(pk23.x);
      Pt[w][base + 48] = bfbits(pk23.y);
    }
    __asm__ volatile("s_waitcnt lgkmcnt(0)" ::: "memory");
    const short8 aP0 = *(const short8*)&Pt[w][lr * 68 + qd * 8];
    const short8 aP1 = *(const short8*)&Pt[w][lr * 68 + 32 + qd * 8];

    // ---- rescale O, P @ V ----
#pragma unroll
    for (int d = 0; d < 4; d++)
#pragma unroll
      for (int r = 0; r < 4; r++) accO[d][r] *= al[r];
#pragma unroll
    for (int d = 0; d < 4; d++) {
      const short8 bV0 = *(const short8*)&Vt[(d * 16 + lr) * 64 + c0];
      const short8 bV1 = *(const short8*)&Vt[(d * 16 + lr) * 64 + c1];
      accO[d] = mfma16(aP0, bV0, accO[d]);
      accO[d] = mfma16(aP1, bV1, accO[d]);
    }
  }

  // ---- epilogue ----
#pragma unroll
  for (int d = 0; d < 4; d++)
#pragma unroll
    for (int r = 0; r < 4; r++) {
      const int iG = i0 + w * 16 + qd * 4 + r;
      const float o = accO[d][r] / l_run[r];
      ab[(size_t)(b * S_ + iG) * 1024 + h * 64 + d * 16 + lr] = f2bf(o);
    }
}

// ---------------- launch ----------------
extern "C" void kernel_launch(void* const* d_in, const int* in_sizes, int n_in,
                              void* d_out, int out_size, void* d_ws, size_t ws_size,
                              hipStream_t stream) {
  const float* hidden = (const float*)d_in[0];
  const float* pos    = (const float*)d_in[1];
  const float* memory = (const float*)d_in[2];
  // d_in[3] = mask (bool) — causality applied analytically, unused
  const float* Wq = (const float*)d_in[4];
  const float* Wk = (const float*)d_in[5];
  const float* Wv = (const float*)d_in[6];
  const float* Wo = (const float*)d_in[7];
  const float* gamma = (const float*)d_in[8];
  const float* beta  = (const float*)d_in[9];

  char* ws = (char*)d_ws;
  u16* cln  = (u16*)(ws);               // B*K*D bf16  = 8 MB
  u16* qb   = (u16*)(ws + 8388608);     // 4 MB  [b][s][h*64+dh]
  u16* kb   = (u16*)(ws + 12582912);    // 8 MB  [b][key][h*64+dh]
  u16* vbT  = (u16*)(ws + 20971520);    // 8 MB  [b*H+h][dh][key]
  u16* ab   = (u16*)(ws + 29360128);    // 4 MB
  u16* WqT  = (u16*)(ws + 33554432);    // 4 x 2 MB transposed bf16 weights (contiguous)
  u16* WkT  = WqT + 1048576;
  u16* WvT  = WkT + 1048576;
  u16* WoT  = WvT + 1048576;
  u16* posb = (u16*)(ws + 41943040);    // B*R*64 bf16 ≈ 1.0 MB

  prep_kernel<<<dim3(5632), 256, 0, stream>>>(
      hidden, memory, gamma, beta, cln,
      Wq, Wk, Wv, Wo, WqT, WkT, WvT, WoT, pos, posb);
  // fused QKV: A = c_ln (4096 rows), Bt = WqT||WkT||WvT, N = 3072
  gemm_bt_kernel<<<dim3(24, 32), 256, 0, stream>>>(
      cln, WqT, qb, kb, vbT, nullptr, nullptr, 1024, 0, 0, 1);
  attn_kernel<<<dim3(S_ / 64, H_, B_), 256, 0, stream>>>(qb, kb, vbT, posb, ab);
  // out = h_ln + attn @ Wo
  gemm_bt_kernel<<<dim3(8, 16), 256, 0, stream>>>(
      ab, WoT, nullptr, nullptr, nullptr, (float*)d_out, cln, 1024, 0, 1, 0);
}